// Round 17
// baseline (290.396 us; speedup 1.0000x reference)
//
#include <hip/hip_runtime.h>
#include <hip/hip_bf16.h>

// GCN layer: N=100000, E=1600000, IN=256, OUT=32, fp32.
// R25 post-mortem: bf16-h was null (254.7->254.1) — sort_agg is request-
// bound, not byte-bound. Kept bf16 (free, halves gemm writes).
// R26: (1) gemm rewrite — R16's gemm issued 512 ds_read_b128/wave (~31us
// of LDS pipe/CU = the 59us). New mapping: lane = 1 row x 32 cols
// (wave = 64 rows, 2 waves/block): A-reads drop to 64 b128/wave (8x) and
// W leaves LDS entirely — W[k*32+c] is wave-uniform -> s_load/SGPR FMA
// (or L1 broadcast). No sW/sScale/barriers; per-wave global_load_lds +
// counted vmcnt(4) (proven R16 pattern, plain HIP). Floor ~20-30us.
// (2) src_count: u32-vectorized u8 loads (4 edges/thread, G13).
// Pipeline: memset(cursors) -> partition_fused -> src_count -> gemm ->
//           sort_agg.

#define IN_F 256
#define OUT_F 32

#define G_ROWS 128

// buckets / partition
#define BSHIFT 7
#define BNODES 128
#define NBK 1024
#define PB_EDGES 8192
#define AGG_CAP 4096
#define SLAB 8192

__device__ __forceinline__ unsigned short f2bf(float x) {
  unsigned u = __float_as_uint(x);
  unsigned r = (u + 0x7FFFu + ((u >> 16) & 1u)) >> 16;
  return (unsigned short)r;
}
__device__ __forceinline__ float bf2f(unsigned short b) {
  return __uint_as_float((unsigned)b << 16);
}

// ---------------- fast path ----------------

// Fused partitions with slab reservation: blocks [0,npb) partition src ->
// pairs_s slabs (u8 low bits); blocks [npb,2npb) partition dst -> pairs
// slabs (u32 src|dstlow<<17). Placement via one global atomicAdd per
// (block,bucket) on curS/curD.
__global__ __launch_bounds__(1024) void partition_fused_kernel(
    const int* __restrict__ src, const int* __restrict__ dst,
    int* __restrict__ curS, int* __restrict__ curD,
    unsigned char* __restrict__ pairs_s, unsigned* __restrict__ pairs,
    int E, int npb) {
  __shared__ unsigned sbuf[PB_EDGES];   // 32 KB (u8 view for src role)
  __shared__ int hist[NBK];
  __shared__ int lbase[NBK + 1];
  __shared__ int gbase[NBK];
  __shared__ int wsum[16];

  int tid = threadIdx.x;
  bool isDst = (int)blockIdx.x >= npb;
  int pb = isDst ? (int)blockIdx.x - npb : (int)blockIdx.x;
  hist[tid] = 0;
  __syncthreads();

  int e0 = pb * PB_EDGES + tid * 8;
  int myb[8], myslot[8];
  unsigned mypk[8];
  unsigned char mylow[8];
  if (!isDst) {
    if (e0 + 8 <= E) {
      int4 a0 = ((const int4*)(src + e0))[0], a1 = ((const int4*)(src + e0))[1];
      int ss[8] = {a0.x, a0.y, a0.z, a0.w, a1.x, a1.y, a1.z, a1.w};
#pragma unroll
      for (int j = 0; j < 8; ++j) {
        int b = ss[j] >> BSHIFT;
        myb[j] = b;
        mylow[j] = (unsigned char)(ss[j] & (BNODES - 1));
        myslot[j] = atomicAdd(&hist[b], 1);
      }
    } else {
#pragma unroll
      for (int j = 0; j < 8; ++j) {
        int e = e0 + j;
        if (e < E) {
          int s = src[e];
          int b = s >> BSHIFT;
          myb[j] = b;
          mylow[j] = (unsigned char)(s & (BNODES - 1));
          myslot[j] = atomicAdd(&hist[b], 1);
        } else {
          myb[j] = -1;
        }
      }
    }
  } else {
    if (e0 + 8 <= E) {
      int4 a0 = ((const int4*)(src + e0))[0], a1 = ((const int4*)(src + e0))[1];
      int4 b0 = ((const int4*)(dst + e0))[0], b1 = ((const int4*)(dst + e0))[1];
      int ss[8] = {a0.x, a0.y, a0.z, a0.w, a1.x, a1.y, a1.z, a1.w};
      int dd[8] = {b0.x, b0.y, b0.z, b0.w, b1.x, b1.y, b1.z, b1.w};
#pragma unroll
      for (int j = 0; j < 8; ++j) {
        int b = dd[j] >> BSHIFT;
        myb[j] = b;
        mypk[j] = (unsigned)ss[j] | ((unsigned)(dd[j] & (BNODES - 1)) << 17);
        myslot[j] = atomicAdd(&hist[b], 1);
      }
    } else {
#pragma unroll
      for (int j = 0; j < 8; ++j) {
        int e = e0 + j;
        if (e < E) {
          int s = src[e], d = dst[e];
          int b = d >> BSHIFT;
          myb[j] = b;
          mypk[j] = (unsigned)s | ((unsigned)(d & (BNODES - 1)) << 17);
          myslot[j] = atomicAdd(&hist[b], 1);
        } else {
          myb[j] = -1;
        }
      }
    }
  }
  __syncthreads();

  {
    int v = hist[tid];
    int x = v;
#pragma unroll
    for (int d = 1; d < 64; d <<= 1) {
      int y = __shfl_up(x, d, 64);
      if ((tid & 63) >= d) x += y;
    }
    if ((tid & 63) == 63) wsum[tid >> 6] = x;
    __syncthreads();
    int off = 0;
#pragma unroll
    for (int w = 0; w < 16; ++w)
      if (w < (tid >> 6)) off += wsum[w];
    lbase[tid] = off + x - v;
    if (tid == NBK - 1) lbase[NBK] = off + x;
    // slab reservation: one global atomic per nonzero (block,bucket)
    if (v > 0) {
      int* cur = isDst ? curD : curS;
      int old = atomicAdd(&cur[tid], v);
      gbase[tid] = tid * SLAB + old;
    }
  }
  __syncthreads();

  if (!isDst) {
    unsigned char* sbuf8 = (unsigned char*)sbuf;
#pragma unroll
    for (int j = 0; j < 8; ++j)
      if (myb[j] >= 0) sbuf8[lbase[myb[j]] + myslot[j]] = mylow[j];
  } else {
#pragma unroll
    for (int j = 0; j < 8; ++j)
      if (myb[j] >= 0) sbuf[lbase[myb[j]] + myslot[j]] = mypk[j];
  }
  __syncthreads();

  int total = lbase[NBK];
  int idx = tid * 8;
  if (idx < total) {
    int lo = 0, hi = NBK;
    while (hi - lo > 1) {
      int mid = (lo + hi) >> 1;
      if (lbase[mid] <= idx) lo = mid; else hi = mid;
    }
    int b = lo;
    if (!isDst) {
      unsigned char* sbuf8 = (unsigned char*)sbuf;
#pragma unroll
      for (int j = 0; j < 8; ++j, ++idx) {
        if (idx >= total) break;
        while (idx >= lbase[b + 1]) ++b;
        pairs_s[gbase[b] + (idx - lbase[b])] = sbuf8[idx];
      }
    } else {
#pragma unroll
      for (int j = 0; j < 8; ++j, ++idx) {
        if (idx >= total) break;
        while (idx >= lbase[b + 1]) ++b;
        pairs[gbase[b] + (idx - lbase[b])] = sbuf[idx];
      }
    }
  }
}

// u32-vectorized u8 histogram (4 edges/thread/iter); slab base is 4B
// aligned (SLAB multiple of 4).
__global__ __launch_bounds__(256) void src_count_kernel(
    const unsigned char* __restrict__ pairs_s, const int* __restrict__ cntS,
    float* __restrict__ scale_out, int N) {
  __shared__ int hist[BNODES];
  int tid = threadIdx.x;
  int b = blockIdx.x;
  if (tid < BNODES) hist[tid] = 0;
  __syncthreads();
  int s = b * SLAB;
  int cnt = cntS[b];
  int vec = cnt & ~3;
  for (int i = tid * 4; i < vec; i += 1024) {
    unsigned v = *(const unsigned*)(pairs_s + s + i);
    atomicAdd(&hist[v & 255u], 1);
    atomicAdd(&hist[(v >> 8) & 255u], 1);
    atomicAdd(&hist[(v >> 16) & 255u], 1);
    atomicAdd(&hist[v >> 24], 1);
  }
  if (tid < cnt - vec) atomicAdd(&hist[pairs_s[s + vec + tid]], 1);
  __syncthreads();
  if (tid < BNODES) {
    int node = (b << BSHIFT) + tid;
    if (node < N) {
      int c = hist[tid];
      scale_out[node] = (c < 1) ? 1.f : rsqrtf((float)c);
    }
  }
}

// h[n][o] = bf16( scale_out[n] * sum_k feat[n][k] * W[k][o] )
// Lane = 1 row x 32 cols; wave = 64 rows; 2 waves/block (G_ROWS=128).
// feat staged per-wave via global_load_lds (4 instrs/tile, counted
// vmcnt(4), no barriers). W read at wave-uniform addresses (s_load /
// L1 broadcast). A-reads: 4 ds_read_b128 per tile per lane.
__global__ __launch_bounds__(128) void gemm_kernel(
    const float* __restrict__ feat, const float* __restrict__ W,
    const float* __restrict__ scale_out, unsigned short* __restrict__ h,
    int N) {
  __shared__ float sF[2][2][64 * 16];   // [wave][buf][64 rows x 16 k] 16KB

  int tid = threadIdx.x;
  int wv = tid >> 6;
  int lane = tid & 63;
  int wrow0 = blockIdx.x * G_ROWS + wv * 64;
  int myrow = wrow0 + lane;
  int rowc = myrow < N ? myrow : N - 1;

  auto stage = [&](int t) {
    float* dstb = &sF[wv][t & 1][0];
    int k0 = t * 16;
#pragma unroll
    for (int q = 0; q < 4; ++q) {
      int p = q * 64 + lane;          // chunk index: row = p>>2, c = p&3
      int g = wrow0 + (p >> 2);
      if (g >= N) g = N - 1;
      const float* gp = feat + (size_t)g * IN_F + k0 + (p & 3) * 4;
      __builtin_amdgcn_global_load_lds(
          (const __attribute__((address_space(1))) unsigned int*)gp,
          (__attribute__((address_space(3))) unsigned int*)(dstb + p * 4),
          16, 0, 0);
    }
  };

  float acc[32];
#pragma unroll
  for (int c = 0; c < 32; ++c) acc[c] = 0.f;

  stage(0);

  for (int t = 0; t < 16; ++t) {
    if (t + 1 < 16) {
      stage(t + 1);
      asm volatile("s_waitcnt vmcnt(4)" ::: "memory");
    } else {
      asm volatile("s_waitcnt vmcnt(0)" ::: "memory");
    }

    const float* sf = &sF[wv][t & 1][0];
    int kb = t * 16;
#pragma unroll
    for (int kk = 0; kk < 4; ++kk) {
      // lane's row chunk kk: 4 consecutive k values
      float4 a4 = *(const float4*)(sf + lane * 16 + kk * 4);
#pragma unroll
      for (int j = 0; j < 4; ++j) {
        float aj = (j == 0) ? a4.x : (j == 1) ? a4.y : (j == 2) ? a4.z : a4.w;
        const float* wrow = W + (size_t)(kb + kk * 4 + j) * OUT_F;
#pragma unroll
        for (int c4 = 0; c4 < 8; ++c4) {
          float4 w = *(const float4*)(wrow + c4 * 4);   // wave-uniform
          acc[c4 * 4 + 0] = fmaf(aj, w.x, acc[c4 * 4 + 0]);
          acc[c4 * 4 + 1] = fmaf(aj, w.y, acc[c4 * 4 + 1]);
          acc[c4 * 4 + 2] = fmaf(aj, w.z, acc[c4 * 4 + 2]);
          acc[c4 * 4 + 3] = fmaf(aj, w.w, acc[c4 * 4 + 3]);
        }
      }
    }
  }

  float sc = scale_out[rowc];
  if (myrow < N) {
    unsigned short* hp = h + (size_t)myrow * OUT_F;
#pragma unroll
    for (int c4 = 0; c4 < 8; ++c4) {
      ushort4 o;
      o.x = f2bf(acc[c4 * 4 + 0] * sc);
      o.y = f2bf(acc[c4 * 4 + 1] * sc);
      o.z = f2bf(acc[c4 * 4 + 2] * sc);
      o.w = f2bf(acc[c4 * 4 + 3] * sc);
      *(ushort4*)(hp + c4 * 4) = o;
    }
  }
}

// Per 128-node dst bucket: counting-sort by dstlow, register-accumulate
// runs. Gather phase: 8 independent bf16 loads batched BEFORE any adds.
__global__ __launch_bounds__(256) void sort_agg_kernel(
    const unsigned* __restrict__ pairs, const int* __restrict__ cntD,
    const unsigned short* __restrict__ h, const float* __restrict__ bias,
    float* __restrict__ out, int N) {
  __shared__ unsigned spk[AGG_CAP];   // 16 KB
  __shared__ int hist[BNODES];
  __shared__ int rs[BNODES + 1];
  __shared__ int wsum2[4];

  int tid = threadIdx.x;
  int lane = tid & 31;
  int eg = tid >> 5;
  int b = blockIdx.x;
  int start = b * SLAB;
  int end = start + cntD[b];

  float acc[16];
  int degc[16];
#pragma unroll
  for (int t = 0; t < 16; ++t) { acc[t] = 0.f; degc[t] = 0; }

  for (int chunk = start; chunk < end; chunk += AGG_CAP) {
    int cnt = min(end - chunk, AGG_CAP);
    if (tid < BNODES) hist[tid] = 0;
    __syncthreads();

    unsigned mypk[16];
    int myslot[16];
    int nmine = 0;
    for (int i = tid; i < cnt; i += 256) {
      unsigned pk = pairs[chunk + i];
      mypk[nmine] = pk;
      myslot[nmine] = atomicAdd(&hist[pk >> 17], 1);
      ++nmine;
    }
    __syncthreads();

    {
      int v = (tid < BNODES) ? hist[tid] : 0;
      int x = v;
#pragma unroll
      for (int d = 1; d < 64; d <<= 1) {
        int y = __shfl_up(x, d, 64);
        if ((tid & 63) >= d) x += y;
      }
      if ((tid & 63) == 63) wsum2[tid >> 6] = x;
      __syncthreads();
      int off = (tid >= 64 && tid < BNODES) ? wsum2[0] : 0;
      if (tid < BNODES) rs[tid] = off + x - v;
      if (tid == BNODES - 1) rs[BNODES] = off + x;
    }
    __syncthreads();

    for (int i = 0; i < nmine; ++i) {
      unsigned pk = mypk[i];
      spk[rs[pk >> 17] + myslot[i]] = pk;
    }
    __syncthreads();

#pragma unroll 1
    for (int t = 0; t < 16; ++t) {
      int n = eg * 16 + t;
      int a = rs[n], bnd = rs[n + 1];
      degc[t] += bnd - a;
      float s = acc[t];
      int j = a;
      for (; j + 8 <= bnd; j += 8) {
        unsigned p0 = spk[j], p1 = spk[j + 1], p2 = spk[j + 2], p3 = spk[j + 3];
        unsigned p4 = spk[j + 4], p5 = spk[j + 5], p6 = spk[j + 6], p7 = spk[j + 7];
        float f0 = bf2f(h[(size_t)(p0 & 0x1FFFF) * OUT_F + lane]);
        float f1 = bf2f(h[(size_t)(p1 & 0x1FFFF) * OUT_F + lane]);
        float f2 = bf2f(h[(size_t)(p2 & 0x1FFFF) * OUT_F + lane]);
        float f3 = bf2f(h[(size_t)(p3 & 0x1FFFF) * OUT_F + lane]);
        float f4 = bf2f(h[(size_t)(p4 & 0x1FFFF) * OUT_F + lane]);
        float f5 = bf2f(h[(size_t)(p5 & 0x1FFFF) * OUT_F + lane]);
        float f6 = bf2f(h[(size_t)(p6 & 0x1FFFF) * OUT_F + lane]);
        float f7 = bf2f(h[(size_t)(p7 & 0x1FFFF) * OUT_F + lane]);
        s += ((f0 + f1) + (f2 + f3)) + ((f4 + f5) + (f6 + f7));
      }
      if (j + 4 <= bnd) {
        unsigned p0 = spk[j], p1 = spk[j + 1], p2 = spk[j + 2], p3 = spk[j + 3];
        float f0 = bf2f(h[(size_t)(p0 & 0x1FFFF) * OUT_F + lane]);
        float f1 = bf2f(h[(size_t)(p1 & 0x1FFFF) * OUT_F + lane]);
        float f2 = bf2f(h[(size_t)(p2 & 0x1FFFF) * OUT_F + lane]);
        float f3 = bf2f(h[(size_t)(p3 & 0x1FFFF) * OUT_F + lane]);
        s += (f0 + f1) + (f2 + f3);
        j += 4;
      }
      for (; j < bnd; ++j)
        s += bf2f(h[(size_t)(spk[j] & 0x1FFFF) * OUT_F + lane]);
      acc[t] = s;
    }
    __syncthreads();
  }

  int node0 = b << BSHIFT;
#pragma unroll
  for (int t = 0; t < 16; ++t) {
    int node = node0 + eg * 16 + t;
    if (node < N) {
      float sc = degc[t] > 0 ? rsqrtf((float)degc[t]) : 1.f;
      out[(size_t)node * OUT_F + lane] = fmaxf(fmaf(acc[t], sc, bias[lane]), 0.f);
    }
  }
}

// ---------------- fallback (float-atomic) path ----------------
__global__ __launch_bounds__(256) void degree_kernel(
    const int* __restrict__ src, const int* __restrict__ dst,
    int* __restrict__ cnt_out, int* __restrict__ cnt_in, int E) {
  int i = blockIdx.x * 256 + threadIdx.x;
  if (i < E) {
    atomicAdd(cnt_out + src[i], 1);
    atomicAdd(cnt_in + dst[i], 1);
  }
}

__global__ __launch_bounds__(256) void cnt_to_scale_kernel(
    const int* __restrict__ cnt, float* __restrict__ scale, int N) {
  int i = blockIdx.x * 256 + threadIdx.x;
  if (i < N) {
    int c = cnt[i];
    scale[i] = (c < 1) ? 1.f : rsqrtf((float)c);
  }
}

__global__ __launch_bounds__(256) void aggregate_kernel(
    const int* __restrict__ src, const int* __restrict__ dst,
    const unsigned short* __restrict__ h, float* __restrict__ out, int E) {
  int lane = threadIdx.x & 31;
  int e = (blockIdx.x * 256 + threadIdx.x) >> 5;
  if (e >= E) return;
  float v = bf2f(h[(size_t)src[e] * OUT_F + lane]);
  unsafeAtomicAdd(out + (size_t)dst[e] * OUT_F + lane, v);
}

__global__ __launch_bounds__(256) void finalize_kernel(
    float* __restrict__ out, const int* __restrict__ cnt_in,
    const float* __restrict__ bias, int N) {
  int idx = blockIdx.x * 256 + threadIdx.x;
  if (idx >= N * 8) return;
  int n = idx >> 3;
  int o = (idx & 7) * 4;
  float dg = (float)cnt_in[n];
  float s = dg < 1.f ? 1.f : rsqrtf(dg);
  float4 bv = *(const float4*)(bias + o);
  float4 v = ((const float4*)out)[idx];
  v.x = fmaxf(fmaf(v.x, s, bv.x), 0.f);
  v.y = fmaxf(fmaf(v.y, s, bv.y), 0.f);
  v.z = fmaxf(fmaf(v.z, s, bv.z), 0.f);
  v.w = fmaxf(fmaf(v.w, s, bv.w), 0.f);
  ((float4*)out)[idx] = v;
}

extern "C" void kernel_launch(void* const* d_in, const int* in_sizes, int n_in,
                              void* d_out, int out_size, void* d_ws, size_t ws_size,
                              hipStream_t stream) {
  const float* feat = (const float*)d_in[0];
  const int* src = (const int*)d_in[1];
  const int* dst = (const int*)d_in[2];
  const float* weight = (const float*)d_in[3];
  const float* bias = (const float*)d_in[4];
  float* out = (float*)d_out;

  int N = in_sizes[0] / IN_F;
  int E = in_sizes[1];
  int nb = (N + BNODES - 1) >> BSHIFT;
  int npb = (E + PB_EDGES - 1) / PB_EDGES;

  unsigned short* h = (unsigned short*)d_ws;                 // N*32 bf16
  unsigned* pairs = (unsigned*)(h + (size_t)N * OUT_F);      // NBK*SLAB u32
  unsigned char* pairs_s =
      (unsigned char*)(pairs + (size_t)NBK * SLAB);          // NBK*SLAB u8
  int* curS = (int*)(pairs_s + (size_t)NBK * SLAB);          // NBK
  int* curD = curS + NBK;                                    // NBK
  float* scale_out = (float*)(curD + NBK);                   // N f32

  size_t need = (size_t)N * OUT_F * 2 + (size_t)NBK * SLAB * 5 +
                2 * NBK * 4 + (size_t)N * 4;
  // slab capacity: uniform random max bucket ~ avg + 6*sqrt(avg); gate
  // on avg <= 3072 so max ~3400 << 8192.
  bool fast = (ws_size >= need) && (N <= (1 << 17)) && (nb <= NBK) &&
              ((size_t)E <= (size_t)3072 * nb);

  if (fast) {
    hipMemsetAsync(curS, 0, 2 * NBK * sizeof(int), stream);
    partition_fused_kernel<<<2 * npb, 1024, 0, stream>>>(
        src, dst, curS, curD, pairs_s, pairs, E, npb);
    src_count_kernel<<<nb, 256, 0, stream>>>(pairs_s, curS, scale_out, N);
    gemm_kernel<<<(N + G_ROWS - 1) / G_ROWS, 128, 0, stream>>>(
        feat, weight, scale_out, h, N);
    sort_agg_kernel<<<nb, 256, 0, stream>>>(pairs, curD, h, bias, out, N);
  } else {
    int* cnt_out = (int*)(h + (size_t)N * OUT_F);
    int* cnt_in = cnt_out + N;
    hipMemsetAsync(cnt_out, 0, (size_t)2 * N * sizeof(int), stream);
    hipMemsetAsync(out, 0, (size_t)N * OUT_F * sizeof(float), stream);
    degree_kernel<<<(E + 255) / 256, 256, 0, stream>>>(src, dst, cnt_out, cnt_in, E);
    cnt_to_scale_kernel<<<(N + 255) / 256, 256, 0, stream>>>(
        cnt_out, (float*)cnt_out, N);
    gemm_kernel<<<(N + G_ROWS - 1) / G_ROWS, 128, 0, stream>>>(
        feat, weight, (const float*)cnt_out, h, N);
    aggregate_kernel<<<(E + 7) / 8, 256, 0, stream>>>(src, dst, h, out, E);
    finalize_kernel<<<(N * 8 + 255) / 256, 256, 0, stream>>>(out, cnt_in, bias, N);
  }
}

// Round 18
// 253.182 us; speedup vs baseline: 1.1470x; 1.1470x over previous
//
#include <hip/hip_runtime.h>
#include <hip/hip_bf16.h>

// GCN layer: N=100000, E=1600000, IN=256, OUT=32, fp32.
// R26 post-mortem: lane=row gemm is structurally grid-starved (N/64 =
// 1563 waves = 6/CU, occupancy 17%) + 2-way LDS conflicts + non-scalar
// W loads -> 93us. After 10 rounds, the R16-structure gemm (~59us) is
// declared the local optimum — permanently reverted (with bf16 output).
// R27 keeps R26's u32-vectorized src_count (untested in isolation) for
// clean attribution against R25's 254.1us.
// Pipeline: memset(cursors) -> partition_fused -> src_count -> gemm ->
//           sort_agg.

#define IN_F 256
#define OUT_F 32

#define G_ROWS 128
#define G_BK 16
#define W_ROWS 32
#define G_NT (IN_F / G_BK)

// buckets / partition
#define BSHIFT 7
#define BNODES 128
#define NBK 1024
#define PB_EDGES 8192
#define AGG_CAP 4096
#define SLAB 8192

__device__ __forceinline__ unsigned short f2bf(float x) {
  unsigned u = __float_as_uint(x);
  unsigned r = (u + 0x7FFFu + ((u >> 16) & 1u)) >> 16;
  return (unsigned short)r;
}
__device__ __forceinline__ float bf2f(unsigned short b) {
  return __uint_as_float((unsigned)b << 16);
}

// ---------------- fast path ----------------

// Fused partitions with slab reservation: blocks [0,npb) partition src ->
// pairs_s slabs (u8 low bits); blocks [npb,2npb) partition dst -> pairs
// slabs (u32 src|dstlow<<17). Placement via one global atomicAdd per
// (block,bucket) on curS/curD.
__global__ __launch_bounds__(1024) void partition_fused_kernel(
    const int* __restrict__ src, const int* __restrict__ dst,
    int* __restrict__ curS, int* __restrict__ curD,
    unsigned char* __restrict__ pairs_s, unsigned* __restrict__ pairs,
    int E, int npb) {
  __shared__ unsigned sbuf[PB_EDGES];   // 32 KB (u8 view for src role)
  __shared__ int hist[NBK];
  __shared__ int lbase[NBK + 1];
  __shared__ int gbase[NBK];
  __shared__ int wsum[16];

  int tid = threadIdx.x;
  bool isDst = (int)blockIdx.x >= npb;
  int pb = isDst ? (int)blockIdx.x - npb : (int)blockIdx.x;
  hist[tid] = 0;
  __syncthreads();

  int e0 = pb * PB_EDGES + tid * 8;
  int myb[8], myslot[8];
  unsigned mypk[8];
  unsigned char mylow[8];
  if (!isDst) {
    if (e0 + 8 <= E) {
      int4 a0 = ((const int4*)(src + e0))[0], a1 = ((const int4*)(src + e0))[1];
      int ss[8] = {a0.x, a0.y, a0.z, a0.w, a1.x, a1.y, a1.z, a1.w};
#pragma unroll
      for (int j = 0; j < 8; ++j) {
        int b = ss[j] >> BSHIFT;
        myb[j] = b;
        mylow[j] = (unsigned char)(ss[j] & (BNODES - 1));
        myslot[j] = atomicAdd(&hist[b], 1);
      }
    } else {
#pragma unroll
      for (int j = 0; j < 8; ++j) {
        int e = e0 + j;
        if (e < E) {
          int s = src[e];
          int b = s >> BSHIFT;
          myb[j] = b;
          mylow[j] = (unsigned char)(s & (BNODES - 1));
          myslot[j] = atomicAdd(&hist[b], 1);
        } else {
          myb[j] = -1;
        }
      }
    }
  } else {
    if (e0 + 8 <= E) {
      int4 a0 = ((const int4*)(src + e0))[0], a1 = ((const int4*)(src + e0))[1];
      int4 b0 = ((const int4*)(dst + e0))[0], b1 = ((const int4*)(dst + e0))[1];
      int ss[8] = {a0.x, a0.y, a0.z, a0.w, a1.x, a1.y, a1.z, a1.w};
      int dd[8] = {b0.x, b0.y, b0.z, b0.w, b1.x, b1.y, b1.z, b1.w};
#pragma unroll
      for (int j = 0; j < 8; ++j) {
        int b = dd[j] >> BSHIFT;
        myb[j] = b;
        mypk[j] = (unsigned)ss[j] | ((unsigned)(dd[j] & (BNODES - 1)) << 17);
        myslot[j] = atomicAdd(&hist[b], 1);
      }
    } else {
#pragma unroll
      for (int j = 0; j < 8; ++j) {
        int e = e0 + j;
        if (e < E) {
          int s = src[e], d = dst[e];
          int b = d >> BSHIFT;
          myb[j] = b;
          mypk[j] = (unsigned)s | ((unsigned)(d & (BNODES - 1)) << 17);
          myslot[j] = atomicAdd(&hist[b], 1);
        } else {
          myb[j] = -1;
        }
      }
    }
  }
  __syncthreads();

  {
    int v = hist[tid];
    int x = v;
#pragma unroll
    for (int d = 1; d < 64; d <<= 1) {
      int y = __shfl_up(x, d, 64);
      if ((tid & 63) >= d) x += y;
    }
    if ((tid & 63) == 63) wsum[tid >> 6] = x;
    __syncthreads();
    int off = 0;
#pragma unroll
    for (int w = 0; w < 16; ++w)
      if (w < (tid >> 6)) off += wsum[w];
    lbase[tid] = off + x - v;
    if (tid == NBK - 1) lbase[NBK] = off + x;
    // slab reservation: one global atomic per nonzero (block,bucket)
    if (v > 0) {
      int* cur = isDst ? curD : curS;
      int old = atomicAdd(&cur[tid], v);
      gbase[tid] = tid * SLAB + old;
    }
  }
  __syncthreads();

  if (!isDst) {
    unsigned char* sbuf8 = (unsigned char*)sbuf;
#pragma unroll
    for (int j = 0; j < 8; ++j)
      if (myb[j] >= 0) sbuf8[lbase[myb[j]] + myslot[j]] = mylow[j];
  } else {
#pragma unroll
    for (int j = 0; j < 8; ++j)
      if (myb[j] >= 0) sbuf[lbase[myb[j]] + myslot[j]] = mypk[j];
  }
  __syncthreads();

  int total = lbase[NBK];
  int idx = tid * 8;
  if (idx < total) {
    int lo = 0, hi = NBK;
    while (hi - lo > 1) {
      int mid = (lo + hi) >> 1;
      if (lbase[mid] <= idx) lo = mid; else hi = mid;
    }
    int b = lo;
    if (!isDst) {
      unsigned char* sbuf8 = (unsigned char*)sbuf;
#pragma unroll
      for (int j = 0; j < 8; ++j, ++idx) {
        if (idx >= total) break;
        while (idx >= lbase[b + 1]) ++b;
        pairs_s[gbase[b] + (idx - lbase[b])] = sbuf8[idx];
      }
    } else {
#pragma unroll
      for (int j = 0; j < 8; ++j, ++idx) {
        if (idx >= total) break;
        while (idx >= lbase[b + 1]) ++b;
        pairs[gbase[b] + (idx - lbase[b])] = sbuf[idx];
      }
    }
  }
}

// u32-vectorized u8 histogram (4 edges/thread/iter); slab base is 4B
// aligned (SLAB multiple of 4).
__global__ __launch_bounds__(256) void src_count_kernel(
    const unsigned char* __restrict__ pairs_s, const int* __restrict__ cntS,
    float* __restrict__ scale_out, int N) {
  __shared__ int hist[BNODES];
  int tid = threadIdx.x;
  int b = blockIdx.x;
  if (tid < BNODES) hist[tid] = 0;
  __syncthreads();
  int s = b * SLAB;
  int cnt = cntS[b];
  int vec = cnt & ~3;
  for (int i = tid * 4; i < vec; i += 1024) {
    unsigned v = *(const unsigned*)(pairs_s + s + i);
    atomicAdd(&hist[v & 255u], 1);
    atomicAdd(&hist[(v >> 8) & 255u], 1);
    atomicAdd(&hist[(v >> 16) & 255u], 1);
    atomicAdd(&hist[v >> 24], 1);
  }
  if (tid < cnt - vec) atomicAdd(&hist[pairs_s[s + vec + tid]], 1);
  __syncthreads();
  if (tid < BNODES) {
    int node = (b << BSHIFT) + tid;
    if (node < N) {
      int c = hist[tid];
      scale_out[node] = (c < 1) ? 1.f : rsqrtf((float)c);
    }
  }
}

// h[n][o] = bf16( scale_out[n] * sum_k feat[n][k] * W[k][o] )
// Per-wave private staging, NO k-loop barriers (R16 structure, known-good
// ~59us — declared local optimum after 10 gemm rounds).
__global__ __launch_bounds__(256, 4) void gemm_kernel(
    const float* __restrict__ feat, const float* __restrict__ W,
    const float* __restrict__ scale_out, unsigned short* __restrict__ h,
    int N) {
  __shared__ float sW[IN_F * OUT_F];                 // 32 KB
  __shared__ float sF[4][2][W_ROWS * G_BK];          // 4 waves x 2 bufs x 2KB
  __shared__ float sScale[G_ROWS];

  int tid = threadIdx.x;
  int wv = tid >> 6;
  int lane = tid & 63;
  {
    const float4* W4 = (const float4*)W;
    float4* sW4 = (float4*)sW;
#pragma unroll
    for (int i = 0; i < 8; ++i) sW4[tid + i * 256] = W4[tid + i * 256];
  }
  int grow = blockIdx.x * G_ROWS;
  if (tid < G_ROWS) {
    int gr = grow + tid;
    sScale[tid] = (gr < N) ? scale_out[gr] : 0.f;
  }
  int wrow0 = grow + wv * W_ROWS;

  auto stage = [&](int t) {
    int k0 = t * G_BK;
    float* dstb = &sF[wv][t & 1][0];
#pragma unroll
    for (int q = 0; q < 2; ++q) {
      int r = q * 16 + (lane >> 2);
      int c = (lane & 3) ^ (r & 3);
      int g = wrow0 + r;
      if (g >= N) g = N - 1;
      const float* gp = feat + (size_t)g * IN_F + k0 + c * 4;
      __builtin_amdgcn_global_load_lds(
          (const __attribute__((address_space(1))) unsigned int*)gp,
          (__attribute__((address_space(3))) unsigned int*)(dstb + q * 256 + lane * 4),
          16, 0, 0);
    }
  };

  stage(0);

  int tr = lane >> 3;
  int cg = (lane & 7) * 4;

  float acc[4][4];
#pragma unroll
  for (int i = 0; i < 4; ++i)
#pragma unroll
    for (int c = 0; c < 4; ++c) acc[i][c] = 0.f;

  __syncthreads();

  for (int t = 0; t < G_NT; ++t) {
    if (t + 1 < G_NT) {
      stage(t + 1);
      asm volatile("s_waitcnt vmcnt(2)" ::: "memory");
    } else {
      asm volatile("s_waitcnt vmcnt(0)" ::: "memory");
    }

    const float* sf = &sF[wv][t & 1][0];
    int kb = t * G_BK;
#pragma unroll
    for (int cc = 0; cc < 4; ++cc) {
      float4 a[4];
#pragma unroll
      for (int i = 0; i < 4; ++i) {
        int r = tr + 8 * i;
        a[i] = *(const float4*)(sf + r * 16 + ((cc ^ (r & 3)) << 2));
      }
#pragma unroll
      for (int j = 0; j < 4; ++j) {
        float4 w = *(const float4*)(sW + (kb + cc * 4 + j) * OUT_F + cg);
#pragma unroll
        for (int i = 0; i < 4; ++i) {
          float aj = (j == 0) ? a[i].x : (j == 1) ? a[i].y
                   : (j == 2) ? a[i].z : a[i].w;
          acc[i][0] = fmaf(aj, w.x, acc[i][0]);
          acc[i][1] = fmaf(aj, w.y, acc[i][1]);
          acc[i][2] = fmaf(aj, w.z, acc[i][2]);
          acc[i][3] = fmaf(aj, w.w, acc[i][3]);
        }
      }
    }
  }

#pragma unroll
  for (int i = 0; i < 4; ++i) {
    int r = tr + 8 * i;
    int g = wrow0 + r;
    if (g < N) {
      float s = sScale[wv * W_ROWS + r];
      ushort4 o;
      o.x = f2bf(acc[i][0] * s);
      o.y = f2bf(acc[i][1] * s);
      o.z = f2bf(acc[i][2] * s);
      o.w = f2bf(acc[i][3] * s);
      *(ushort4*)(h + (size_t)g * OUT_F + cg) = o;
    }
  }
}

// Per 128-node dst bucket: counting-sort by dstlow, register-accumulate
// runs. Gather phase: 8 independent bf16 loads batched BEFORE any adds.
__global__ __launch_bounds__(256) void sort_agg_kernel(
    const unsigned* __restrict__ pairs, const int* __restrict__ cntD,
    const unsigned short* __restrict__ h, const float* __restrict__ bias,
    float* __restrict__ out, int N) {
  __shared__ unsigned spk[AGG_CAP];   // 16 KB
  __shared__ int hist[BNODES];
  __shared__ int rs[BNODES + 1];
  __shared__ int wsum2[4];

  int tid = threadIdx.x;
  int lane = tid & 31;
  int eg = tid >> 5;
  int b = blockIdx.x;
  int start = b * SLAB;
  int end = start + cntD[b];

  float acc[16];
  int degc[16];
#pragma unroll
  for (int t = 0; t < 16; ++t) { acc[t] = 0.f; degc[t] = 0; }

  for (int chunk = start; chunk < end; chunk += AGG_CAP) {
    int cnt = min(end - chunk, AGG_CAP);
    if (tid < BNODES) hist[tid] = 0;
    __syncthreads();

    unsigned mypk[16];
    int myslot[16];
    int nmine = 0;
    for (int i = tid; i < cnt; i += 256) {
      unsigned pk = pairs[chunk + i];
      mypk[nmine] = pk;
      myslot[nmine] = atomicAdd(&hist[pk >> 17], 1);
      ++nmine;
    }
    __syncthreads();

    {
      int v = (tid < BNODES) ? hist[tid] : 0;
      int x = v;
#pragma unroll
      for (int d = 1; d < 64; d <<= 1) {
        int y = __shfl_up(x, d, 64);
        if ((tid & 63) >= d) x += y;
      }
      if ((tid & 63) == 63) wsum2[tid >> 6] = x;
      __syncthreads();
      int off = (tid >= 64 && tid < BNODES) ? wsum2[0] : 0;
      if (tid < BNODES) rs[tid] = off + x - v;
      if (tid == BNODES - 1) rs[BNODES] = off + x;
    }
    __syncthreads();

    for (int i = 0; i < nmine; ++i) {
      unsigned pk = mypk[i];
      spk[rs[pk >> 17] + myslot[i]] = pk;
    }
    __syncthreads();

#pragma unroll 1
    for (int t = 0; t < 16; ++t) {
      int n = eg * 16 + t;
      int a = rs[n], bnd = rs[n + 1];
      degc[t] += bnd - a;
      float s = acc[t];
      int j = a;
      for (; j + 8 <= bnd; j += 8) {
        unsigned p0 = spk[j], p1 = spk[j + 1], p2 = spk[j + 2], p3 = spk[j + 3];
        unsigned p4 = spk[j + 4], p5 = spk[j + 5], p6 = spk[j + 6], p7 = spk[j + 7];
        float f0 = bf2f(h[(size_t)(p0 & 0x1FFFF) * OUT_F + lane]);
        float f1 = bf2f(h[(size_t)(p1 & 0x1FFFF) * OUT_F + lane]);
        float f2 = bf2f(h[(size_t)(p2 & 0x1FFFF) * OUT_F + lane]);
        float f3 = bf2f(h[(size_t)(p3 & 0x1FFFF) * OUT_F + lane]);
        float f4 = bf2f(h[(size_t)(p4 & 0x1FFFF) * OUT_F + lane]);
        float f5 = bf2f(h[(size_t)(p5 & 0x1FFFF) * OUT_F + lane]);
        float f6 = bf2f(h[(size_t)(p6 & 0x1FFFF) * OUT_F + lane]);
        float f7 = bf2f(h[(size_t)(p7 & 0x1FFFF) * OUT_F + lane]);
        s += ((f0 + f1) + (f2 + f3)) + ((f4 + f5) + (f6 + f7));
      }
      if (j + 4 <= bnd) {
        unsigned p0 = spk[j], p1 = spk[j + 1], p2 = spk[j + 2], p3 = spk[j + 3];
        float f0 = bf2f(h[(size_t)(p0 & 0x1FFFF) * OUT_F + lane]);
        float f1 = bf2f(h[(size_t)(p1 & 0x1FFFF) * OUT_F + lane]);
        float f2 = bf2f(h[(size_t)(p2 & 0x1FFFF) * OUT_F + lane]);
        float f3 = bf2f(h[(size_t)(p3 & 0x1FFFF) * OUT_F + lane]);
        s += (f0 + f1) + (f2 + f3);
        j += 4;
      }
      for (; j < bnd; ++j)
        s += bf2f(h[(size_t)(spk[j] & 0x1FFFF) * OUT_F + lane]);
      acc[t] = s;
    }
    __syncthreads();
  }

  int node0 = b << BSHIFT;
#pragma unroll
  for (int t = 0; t < 16; ++t) {
    int node = node0 + eg * 16 + t;
    if (node < N) {
      float sc = degc[t] > 0 ? rsqrtf((float)degc[t]) : 1.f;
      out[(size_t)node * OUT_F + lane] = fmaxf(fmaf(acc[t], sc, bias[lane]), 0.f);
    }
  }
}

// ---------------- fallback (float-atomic) path ----------------
__global__ __launch_bounds__(256) void degree_kernel(
    const int* __restrict__ src, const int* __restrict__ dst,
    int* __restrict__ cnt_out, int* __restrict__ cnt_in, int E) {
  int i = blockIdx.x * 256 + threadIdx.x;
  if (i < E) {
    atomicAdd(cnt_out + src[i], 1);
    atomicAdd(cnt_in + dst[i], 1);
  }
}

__global__ __launch_bounds__(256) void cnt_to_scale_kernel(
    const int* __restrict__ cnt, float* __restrict__ scale, int N) {
  int i = blockIdx.x * 256 + threadIdx.x;
  if (i < N) {
    int c = cnt[i];
    scale[i] = (c < 1) ? 1.f : rsqrtf((float)c);
  }
}

__global__ __launch_bounds__(256) void aggregate_kernel(
    const int* __restrict__ src, const int* __restrict__ dst,
    const unsigned short* __restrict__ h, float* __restrict__ out, int E) {
  int lane = threadIdx.x & 31;
  int e = (blockIdx.x * 256 + threadIdx.x) >> 5;
  if (e >= E) return;
  float v = bf2f(h[(size_t)src[e] * OUT_F + lane]);
  unsafeAtomicAdd(out + (size_t)dst[e] * OUT_F + lane, v);
}

__global__ __launch_bounds__(256) void finalize_kernel(
    float* __restrict__ out, const int* __restrict__ cnt_in,
    const float* __restrict__ bias, int N) {
  int idx = blockIdx.x * 256 + threadIdx.x;
  if (idx >= N * 8) return;
  int n = idx >> 3;
  int o = (idx & 7) * 4;
  float dg = (float)cnt_in[n];
  float s = dg < 1.f ? 1.f : rsqrtf(dg);
  float4 bv = *(const float4*)(bias + o);
  float4 v = ((const float4*)out)[idx];
  v.x = fmaxf(fmaf(v.x, s, bv.x), 0.f);
  v.y = fmaxf(fmaf(v.y, s, bv.y), 0.f);
  v.z = fmaxf(fmaf(v.z, s, bv.z), 0.f);
  v.w = fmaxf(fmaf(v.w, s, bv.w), 0.f);
  ((float4*)out)[idx] = v;
}

extern "C" void kernel_launch(void* const* d_in, const int* in_sizes, int n_in,
                              void* d_out, int out_size, void* d_ws, size_t ws_size,
                              hipStream_t stream) {
  const float* feat = (const float*)d_in[0];
  const int* src = (const int*)d_in[1];
  const int* dst = (const int*)d_in[2];
  const float* weight = (const float*)d_in[3];
  const float* bias = (const float*)d_in[4];
  float* out = (float*)d_out;

  int N = in_sizes[0] / IN_F;
  int E = in_sizes[1];
  int nb = (N + BNODES - 1) >> BSHIFT;
  int npb = (E + PB_EDGES - 1) / PB_EDGES;

  unsigned short* h = (unsigned short*)d_ws;                 // N*32 bf16
  unsigned* pairs = (unsigned*)(h + (size_t)N * OUT_F);      // NBK*SLAB u32
  unsigned char* pairs_s =
      (unsigned char*)(pairs + (size_t)NBK * SLAB);          // NBK*SLAB u8
  int* curS = (int*)(pairs_s + (size_t)NBK * SLAB);          // NBK
  int* curD = curS + NBK;                                    // NBK
  float* scale_out = (float*)(curD + NBK);                   // N f32

  size_t need = (size_t)N * OUT_F * 2 + (size_t)NBK * SLAB * 5 +
                2 * NBK * 4 + (size_t)N * 4;
  // slab capacity: uniform random max bucket ~ avg + 6*sqrt(avg); gate
  // on avg <= 3072 so max ~3400 << 8192.
  bool fast = (ws_size >= need) && (N <= (1 << 17)) && (nb <= NBK) &&
              ((size_t)E <= (size_t)3072 * nb);

  if (fast) {
    hipMemsetAsync(curS, 0, 2 * NBK * sizeof(int), stream);
    partition_fused_kernel<<<2 * npb, 1024, 0, stream>>>(
        src, dst, curS, curD, pairs_s, pairs, E, npb);
    src_count_kernel<<<nb, 256, 0, stream>>>(pairs_s, curS, scale_out, N);
    gemm_kernel<<<(N + G_ROWS - 1) / G_ROWS, 256, 0, stream>>>(
        feat, weight, scale_out, h, N);
    sort_agg_kernel<<<nb, 256, 0, stream>>>(pairs, curD, h, bias, out, N);
  } else {
    int* cnt_out = (int*)(h + (size_t)N * OUT_F);
    int* cnt_in = cnt_out + N;
    hipMemsetAsync(cnt_out, 0, (size_t)2 * N * sizeof(int), stream);
    hipMemsetAsync(out, 0, (size_t)N * OUT_F * sizeof(float), stream);
    degree_kernel<<<(E + 255) / 256, 256, 0, stream>>>(src, dst, cnt_out, cnt_in, E);
    cnt_to_scale_kernel<<<(N + 255) / 256, 256, 0, stream>>>(
        cnt_out, (float*)cnt_out, N);
    gemm_kernel<<<(N + G_ROWS - 1) / G_ROWS, 256, 0, stream>>>(
        feat, weight, (const float*)cnt_out, h, N);
    aggregate_kernel<<<(E + 7) / 8, 256, 0, stream>>>(src, dst, h, out, E);
    finalize_kernel<<<(N * 8 + 255) / 256, 256, 0, stream>>>(out, cnt_in, bias, N);
  }
}